// Round 6
// baseline (192.121 us; speedup 1.0000x reference)
//
#include <hip/hip_runtime.h>
#include <hip/hip_fp16.h>

#define KDIM 1024
#define DDIM 64
#define SPAT 32768
#define NVEC 65536
#define DSP  (DDIM * SPAT)          // 2097152
#define MARGIN 1.0e-4f              // approx-gap flag threshold (err bound ~2e-5)

typedef _Float16 half8 __attribute__((ext_vector_type(8)));
typedef float floatx4 __attribute__((ext_vector_type(4)));

__device__ __forceinline__ float opaque(float x) { asm volatile("" : "+v"(x)); return x; }

// Bitwise replica of np.add.reduce pairwise base case over fl(x[d]^2), d=0..63 (R3-proven)
__device__ __forceinline__ float np_sumsq64(const float* x) {
    float r8[8];
#pragma unroll
    for (int j = 0; j < 8; ++j) r8[j] = opaque(x[1 + j] * x[1 + j]);
#pragma unroll
    for (int i = 8; i < 56; i += 8) {
#pragma unroll
        for (int j = 0; j < 8; ++j) r8[j] += opaque(x[1 + i + j] * x[1 + i + j]);
    }
    float res = ((r8[0] + r8[1]) + (r8[2] + r8[3])) + ((r8[4] + r8[5]) + (r8[6] + r8[7]));
#pragma unroll
    for (int m = 57; m < 64; ++m) res += opaque(x[m] * x[m]);
    return opaque(x[0] * x[0]) + res;
}

// K1: per codebook row: h = np-f32 ||e||^2, e2 = 2e (exact), eh/el = fp16 hi/lo of e*1024
__global__ void vq_prep_e(const float* __restrict__ emb, float* __restrict__ e2,
                          float* __restrict__ h, __half* __restrict__ eh,
                          __half* __restrict__ el) {
    int k = blockIdx.x * blockDim.x + threadIdx.x;
    if (k >= KDIM) return;
    float e[DDIM];
#pragma unroll
    for (int d = 0; d < DDIM; ++d) {
        e[d] = emb[k * DDIM + d];
        e2[k * DDIM + d] = e[d] + e[d];
    }
    h[k] = np_sumsq64(e);
#pragma unroll
    for (int j = 0; j < 8; ++j) {
        half8 vh, vl;
#pragma unroll
        for (int u = 0; u < 8; ++u) {
            float es = e[8 * j + u] * 1024.0f;     // exact scale: keeps lo-part fp16-normal
            _Float16 hi = (_Float16)es;
            float df = es - (float)hi;
            vh[u] = hi; vl[u] = (_Float16)df;
        }
        ((half8*)(eh + (size_t)k * DDIM))[j] = vh;
        ((half8*)(el + (size_t)k * DDIM))[j] = vl;
    }
}

// K2: per z row n: sn = np-f32 ||z||^2; zh/zl fp16 hi/lo of z, layout [n][d]
__global__ void vq_prep_z(const float* __restrict__ z, __half* __restrict__ zh,
                          __half* __restrict__ zl, float* __restrict__ sn) {
    const int n = blockIdx.x * blockDim.x + threadIdx.x;
    const int b = n >> 15, s = n & (SPAT - 1);
    const float* zp = z + (size_t)b * DSP + s;
    float zv[DDIM];
#pragma unroll
    for (int d = 0; d < DDIM; ++d) zv[d] = zp[(size_t)d * SPAT];
    sn[n] = np_sumsq64(zv);
#pragma unroll
    for (int j = 0; j < 8; ++j) {
        half8 vh, vl;
#pragma unroll
        for (int u = 0; u < 8; ++u) {
            float x = zv[8 * j + u];
            _Float16 hi = (_Float16)x;
            float df = x - (float)hi;
            vh[u] = hi; vl[u] = (_Float16)df;
        }
        ((half8*)(zh + (size_t)n * DDIM))[j] = vh;
        ((half8*)(zl + (size_t)n * DDIM))[j] = vl;
    }
}

// K3: MFMA approx-distance scan. Block = 64 rows(n) x all K. Wave w: codebook quarter.
// A = E tile (16 k-rows x 32 d), B = Z tile (32 d x 16 n). D[row=codebook][col=n].
__global__ __launch_bounds__(256, 3) void vq_mfma_kernel(
    const __half* __restrict__ zh_, const __half* __restrict__ zl_,
    const __half* __restrict__ eh_, const __half* __restrict__ el_,
    const float* __restrict__ sn_, const float* __restrict__ h_,
    float* __restrict__ idxf, int* __restrict__ cnt, int* __restrict__ wl)
{
    __shared__ float Lm1[16][64];
    __shared__ float Lm2[16][64];
    __shared__ int   Li1[16][64];

    const int tid = threadIdx.x, l = tid & 63, w = tid >> 6;
    const int nbase = blockIdx.x * 64;
    const int col16 = l & 15, g16 = l >> 4;

    // Z fragments resident for whole kernel: [nc][kpass][hi/lo]
    half8 zf[4][2][2];
    float snv[4];
#pragma unroll
    for (int nc = 0; nc < 4; ++nc) {
        const size_t nrow = (size_t)(nbase + nc * 16 + col16) * DDIM;
        snv[nc] = sn_[nbase + nc * 16 + col16];
#pragma unroll
        for (int kp = 0; kp < 2; ++kp) {
            const size_t off = nrow + g16 * 8 + kp * 32;
            zf[nc][kp][0] = *(const half8*)(zh_ + off);
            zf[nc][kp][1] = *(const half8*)(zl_ + off);
        }
    }

    float m1[4], m2[4]; int i1[4];
#pragma unroll
    for (int nc = 0; nc < 4; ++nc) { m1[nc] = 3.0e38f; m2[nc] = 3.0e38f; i1[nc] = 0; }

    const int myk0 = w * 256;
    for (int t = 0; t < 16; ++t) {
        const int krow0 = myk0 + t * 16;
        const size_t eoff = (size_t)(krow0 + col16) * DDIM + g16 * 8;
        half8 ef0h = *(const half8*)(eh_ + eoff);
        half8 ef1h = *(const half8*)(eh_ + eoff + 32);
        half8 ef0l = *(const half8*)(el_ + eoff);
        half8 ef1l = *(const half8*)(el_ + eoff + 32);
        floatx4 hv = *(const floatx4*)(h_ + krow0 + g16 * 4);
        const int rbase = krow0 + g16 * 4;
#pragma unroll
        for (int nc = 0; nc < 4; ++nc) {
            floatx4 acc = {0.f, 0.f, 0.f, 0.f};
            acc = __builtin_amdgcn_mfma_f32_16x16x32_f16(ef0h, zf[nc][0][0], acc, 0, 0, 0);
            acc = __builtin_amdgcn_mfma_f32_16x16x32_f16(ef1h, zf[nc][1][0], acc, 0, 0, 0);
            acc = __builtin_amdgcn_mfma_f32_16x16x32_f16(ef0h, zf[nc][0][1], acc, 0, 0, 0);
            acc = __builtin_amdgcn_mfma_f32_16x16x32_f16(ef1h, zf[nc][1][1], acc, 0, 0, 0);
            acc = __builtin_amdgcn_mfma_f32_16x16x32_f16(ef0l, zf[nc][0][0], acc, 0, 0, 0);
            acc = __builtin_amdgcn_mfma_f32_16x16x32_f16(ef1l, zf[nc][1][0], acc, 0, 0, 0);
#pragma unroll
            for (int j = 0; j < 4; ++j) {
                // dist_approx = (sn + h) - 2*dot;  dot = acc / 1024 (e was pre-scaled)
                float dist = fmaf(-0.001953125f, acc[j], snv[nc] + hv[j]);
                bool lt = dist < m1[nc];
                m2[nc] = lt ? m1[nc] : fminf(m2[nc], dist);
                i1[nc] = lt ? (rbase + j) : i1[nc];
                m1[nc] = lt ? dist : m1[nc];
            }
        }
    }

    const int slot = w * 4 + g16;
#pragma unroll
    for (int nc = 0; nc < 4; ++nc) {
        Lm1[slot][nc * 16 + col16] = m1[nc];
        Lm2[slot][nc * 16 + col16] = m2[nc];
        Li1[slot][nc * 16 + col16] = i1[nc];
    }
    __syncthreads();

    if (tid < 64) {
        float M1 = Lm1[0][tid], M2 = Lm2[0][tid];
        int   I1 = Li1[0][tid];
#pragma unroll
        for (int sI = 1; sI < 16; ++sI) {
            float a1 = Lm1[sI][tid], a2 = Lm2[sI][tid];
            int   ai = Li1[sI][tid];
            if (a1 < M1) { M2 = fminf(M1, a2); M1 = a1; I1 = ai; }
            else         { M2 = fminf(M2, a1); }
        }
        const int n = nbase + tid;
        idxf[n] = (float)I1;
        if (M2 - M1 <= MARGIN) {
            int p = atomicAdd(cnt, 1);
            wl[p] = n;
        }
    }
}

// K4: exact rescan of flagged rows — bit-exact numpy-f32 replica (R3-proven formula)
__global__ void vq_rescan_kernel(const float* __restrict__ z, const float* __restrict__ e2,
                                 const float* __restrict__ h_, const int* __restrict__ cnt,
                                 const int* __restrict__ wl, float* __restrict__ idxf)
{
    const int lane = threadIdx.x & 63;
    int gw = (blockIdx.x * blockDim.x + threadIdx.x) >> 6;
    const int count = *cnt;
    for (; gw < count; gw += 1024) {
        const int n = wl[gw];
        const int b = n >> 15, s = n & (SPAT - 1);
        const float* zp = z + (size_t)b * DSP + s;
        float zv[DDIM];
#pragma unroll
        for (int d = 0; d < DDIM; ++d) zv[d] = zp[(size_t)d * SPAT];
        const float sn = np_sumsq64(zv);

        float best = 3.0e38f; int bidx = 0;
        for (int kk = 0; kk < 16; ++kk) {
            const int k = lane * 16 + kk;             // ascending within lane
            const float* ep = e2 + (size_t)k * DDIM;
            float acc = 0.f;
#pragma unroll
            for (int d = 0; d < DDIM; ++d)
                acc = fmaf(ep[d], zv[d], acc);        // sgemm: sequential f32 FMA from 0
            float t = sn + h_[k];
            float dist = t - acc;
            if (dist < best) { best = dist; bidx = k; }  // strict <: first index wins
        }
#pragma unroll
        for (int off = 32; off > 0; off >>= 1) {
            float ob = __shfl_down(best, off, 64);
            int   oi = __shfl_down(bidx, off, 64);
            if (ob < best || (ob == best && oi < bidx)) { best = ob; bidx = oi; }
        }
        bidx = __shfl(bidx, 0, 64);
        if (lane == 0) idxf[n] = (float)bidx;
    }
}

// K5: gather z_q = emb[idx], write straight-through layout, reduce loss
__global__ void vq_out_kernel(const float* __restrict__ z, const float* __restrict__ emb,
                              const float* __restrict__ idxf, float* __restrict__ zq,
                              float* __restrict__ loss)
{
    __shared__ float wsum[4];
    const int n = blockIdx.x * blockDim.x + threadIdx.x;
    const int b = n >> 15, s = n & (SPAT - 1);
    const int idx = (int)idxf[n];
    const float* e = emb + (size_t)idx * DDIM;
    const float* zp = z + (size_t)b * DSP + s;
    float* op = zq + (size_t)b * DSP + s;
    float lsum = 0.f;
#pragma unroll
    for (int d = 0; d < DDIM; ++d) {
        float q = e[d];
        op[(size_t)d * SPAT] = q;
        float df = q - zp[(size_t)d * SPAT];
        lsum = fmaf(df, df, lsum);
    }
#pragma unroll
    for (int off = 32; off > 0; off >>= 1)
        lsum += __shfl_down(lsum, off, 64);
    if ((threadIdx.x & 63) == 0) wsum[threadIdx.x >> 6] = lsum;
    __syncthreads();
    if (threadIdx.x == 0)
        atomicAdd(loss, (wsum[0] + wsum[1] + wsum[2] + wsum[3]) * (1.25f / 4194304.0f));
}

extern "C" void kernel_launch(void* const* d_in, const int* in_sizes, int n_in,
                              void* d_out, int out_size, void* d_ws, size_t ws_size,
                              hipStream_t stream) {
    const float* z   = (const float*)d_in[0];   // [2, 64, 32, 32, 32]
    const float* emb = (const float*)d_in[1];   // [1024, 64]
    float* out  = (float*)d_out;                // z_q (4194304) | loss (1) | indices (65536)
    float* loss = out + 4194304;
    float* idxf = out + 4194305;

    // zh/zl fp16 planes alias the z_q region (exactly 16 MB); overwritten by K5 last.
    __half* zh = (__half*)out;                  // 65536*64 halves = 8 MB
    __half* zl = zh + (size_t)NVEC * DDIM;      // next 8 MB

    // ws layout (floats)
    float* sn_ = (float*)d_ws;                  // [65536]
    float* h_  = sn_ + NVEC;                    // [1024]
    float* e2_ = h_ + KDIM;                     // [1024*64]
    __half* eh_ = (__half*)(e2_ + KDIM * DDIM); // [1024*64] halves
    __half* el_ = eh_ + KDIM * DDIM;            // [1024*64] halves
    int* cnt = (int*)(el_ + KDIM * DDIM);       // [1]
    int* wl  = cnt + 1;                         // [65536]

    hipMemsetAsync(loss, 0, sizeof(float), stream);
    hipMemsetAsync(cnt, 0, sizeof(int), stream);
    vq_prep_e<<<KDIM / 256, 256, 0, stream>>>(emb, e2_, h_, eh_, el_);
    vq_prep_z<<<NVEC / 256, 256, 0, stream>>>(z, zh, zl, sn_);
    vq_mfma_kernel<<<NVEC / 64, 256, 0, stream>>>(zh, zl, eh_, el_, sn_, h_, idxf, cnt, wl);
    vq_rescan_kernel<<<256, 256, 0, stream>>>(z, e2_, h_, cnt, wl, idxf);
    vq_out_kernel<<<NVEC / 256, 256, 0, stream>>>(z, emb, idxf, out, loss);
}

// Round 7
// 184.275 us; speedup vs baseline: 1.0426x; 1.0426x over previous
//
#include <hip/hip_runtime.h>
#include <hip/hip_fp16.h>

#define KDIM 1024
#define DDIM 64
#define SPAT 32768
#define NVEC 65536
#define DSP  (DDIM * SPAT)          // 2097152
#define MARGIN 4.0e-5f              // > 2*eps; eps <= ulp(dist<256) + mfma-dot diff

typedef _Float16 half8 __attribute__((ext_vector_type(8)));
typedef float floatx4 __attribute__((ext_vector_type(4)));

#define ZPAD 69                     // LDS row stride in floats (odd -> conflict-free)

__device__ __forceinline__ float opaque(float x) { asm volatile("" : "+v"(x)); return x; }

// Bitwise replica of np.add.reduce pairwise base case over fl(x[d]^2), d=0..63 (R3-proven)
__device__ __forceinline__ float np_sumsq64(const float* x) {
    float r8[8];
#pragma unroll
    for (int j = 0; j < 8; ++j) r8[j] = opaque(x[1 + j] * x[1 + j]);
#pragma unroll
    for (int i = 8; i < 56; i += 8) {
#pragma unroll
        for (int j = 0; j < 8; ++j) r8[j] += opaque(x[1 + i + j] * x[1 + i + j]);
    }
    float res = ((r8[0] + r8[1]) + (r8[2] + r8[3])) + ((r8[4] + r8[5]) + (r8[6] + r8[7]));
#pragma unroll
    for (int m = 57; m < 64; ++m) res += opaque(x[m] * x[m]);
    return opaque(x[0] * x[0]) + res;
}

// K1: h = np-f32 ||e||^2, e2 = 2e (exact), eh/el = fp16 hi/lo of e*1024
__global__ void vq_prep_e(const float* __restrict__ emb, float* __restrict__ e2,
                          float* __restrict__ h, __half* __restrict__ eh,
                          __half* __restrict__ el) {
    int k = blockIdx.x * blockDim.x + threadIdx.x;
    if (k >= KDIM) return;
    float e[DDIM];
#pragma unroll
    for (int d = 0; d < DDIM; ++d) {
        e[d] = emb[k * DDIM + d];
        e2[k * DDIM + d] = e[d] + e[d];
    }
    h[k] = np_sumsq64(e);
#pragma unroll
    for (int j = 0; j < 8; ++j) {
        half8 vh, vl;
#pragma unroll
        for (int u = 0; u < 8; ++u) {
            float es = e[8 * j + u] * 1024.0f;   // exact scale
            _Float16 hi = (_Float16)es;
            vh[u] = hi; vl[u] = (_Float16)(es - (float)hi);
        }
        ((half8*)(eh + (size_t)k * DDIM))[j] = vh;
        ((half8*)(el + (size_t)k * DDIM))[j] = vl;
    }
}

// K3: fused z-stage + hi/lo split + MFMA scan + top2 + epilogue (idx, flags, zq+loss for unflagged)
__global__ __launch_bounds__(256, 2) void vq_mfma_kernel(
    const float* __restrict__ z, const float* __restrict__ emb,
    const __half* __restrict__ eh_, const __half* __restrict__ el_,
    const float* __restrict__ h_, float* __restrict__ out,
    float* __restrict__ loss, float* __restrict__ idxf,
    int* __restrict__ cnt, int* __restrict__ wl)
{
    __shared__ float zrow[64 * ZPAD];     // [row][d], stride 69
    __shared__ float lds_sn[64];
    __shared__ float Lm1[16][64];
    __shared__ float Lm2[16][64];
    __shared__ int   Li1[16][64];

    const int tid = threadIdx.x, l = tid & 63, w = tid >> 6;
    const int nbase = blockIdx.x * 64;
    const int b = nbase >> 15, s0 = nbase & (SPAT - 1);
    const int col16 = l & 15, g16 = l >> 4;
    const float* zbase = z + (size_t)b * DSP + s0;

    // stage 64 z-rows: wave w loads d in [w*16, w*16+16), lane = row (coalesced 256B)
    {
        const int dbase = w * 16;
#pragma unroll
        for (int j = 0; j < 16; ++j)
            zrow[l * ZPAD + dbase + j] = zbase[(size_t)(dbase + j) * SPAT + l];
    }
    __syncthreads();

    if (tid < 64) lds_sn[tid] = np_sumsq64(&zrow[tid * ZPAD]);

    // build resident Z fragments: zf[nc][kp][hi/lo]
    half8 zf[4][2][2];
#pragma unroll
    for (int nc = 0; nc < 4; ++nc) {
        const int r = nc * 16 + col16;
#pragma unroll
        for (int kp = 0; kp < 2; ++kp) {
            const int d0 = g16 * 8 + kp * 32;
            half8 vh, vl;
#pragma unroll
            for (int u = 0; u < 8; ++u) {
                float x = zrow[r * ZPAD + d0 + u];
                _Float16 hi = (_Float16)x;
                vh[u] = hi; vl[u] = (_Float16)(x - (float)hi);
            }
            zf[nc][kp][0] = vh; zf[nc][kp][1] = vl;
        }
    }
    __syncthreads();

    float snv[4];
#pragma unroll
    for (int nc = 0; nc < 4; ++nc) snv[nc] = lds_sn[nc * 16 + col16];

    float m1[4], m2[4]; int i1[4];
#pragma unroll
    for (int nc = 0; nc < 4; ++nc) { m1[nc] = 3.0e38f; m2[nc] = 3.0e38f; i1[nc] = 0; }

    const int myk0 = w * 256;
    for (int t = 0; t < 16; ++t) {
        const int krow0 = myk0 + t * 16;
        const size_t eoff = (size_t)(krow0 + col16) * DDIM + g16 * 8;
        half8 ef0h = *(const half8*)(eh_ + eoff);
        half8 ef1h = *(const half8*)(eh_ + eoff + 32);
        half8 ef0l = *(const half8*)(el_ + eoff);
        half8 ef1l = *(const half8*)(el_ + eoff + 32);
        floatx4 hv = *(const floatx4*)(h_ + krow0 + g16 * 4);
        const int rbase = krow0 + g16 * 4;
#pragma unroll
        for (int nc = 0; nc < 4; ++nc) {
            floatx4 acc = {0.f, 0.f, 0.f, 0.f};
            acc = __builtin_amdgcn_mfma_f32_16x16x32_f16(ef0h, zf[nc][0][0], acc, 0, 0, 0);
            acc = __builtin_amdgcn_mfma_f32_16x16x32_f16(ef1h, zf[nc][1][0], acc, 0, 0, 0);
            acc = __builtin_amdgcn_mfma_f32_16x16x32_f16(ef0h, zf[nc][0][1], acc, 0, 0, 0);
            acc = __builtin_amdgcn_mfma_f32_16x16x32_f16(ef1h, zf[nc][1][1], acc, 0, 0, 0);
            acc = __builtin_amdgcn_mfma_f32_16x16x32_f16(ef0l, zf[nc][0][0], acc, 0, 0, 0);
            acc = __builtin_amdgcn_mfma_f32_16x16x32_f16(ef1l, zf[nc][1][0], acc, 0, 0, 0);
#pragma unroll
            for (int j = 0; j < 4; ++j) {
                // dist = fl( fl(sn+h) - 2^-9 * acc )   (acc = 1024*dot)
                float dist = fmaf(-0.001953125f, acc[j], snv[nc] + hv[j]);
                bool lt = dist < m1[nc];
                m2[nc] = lt ? m1[nc] : fminf(m2[nc], dist);
                i1[nc] = lt ? (rbase + j) : i1[nc];
                m1[nc] = lt ? dist : m1[nc];
            }
        }
    }

    const int slot = w * 4 + g16;
#pragma unroll
    for (int nc = 0; nc < 4; ++nc) {
        Lm1[slot][nc * 16 + col16] = m1[nc];
        Lm2[slot][nc * 16 + col16] = m2[nc];
        Li1[slot][nc * 16 + col16] = i1[nc];
    }
    __syncthreads();

    if (tid < 64) {
        float M1 = Lm1[0][tid], M2 = Lm2[0][tid];
        int   I1 = Li1[0][tid];
#pragma unroll
        for (int sI = 1; sI < 16; ++sI) {
            float a1 = Lm1[sI][tid], a2 = Lm2[sI][tid];
            int   ai = Li1[sI][tid];
            if (a1 < M1) { M2 = fminf(M1, a2); M1 = a1; I1 = ai; }
            else         { M2 = fminf(M2, a1); }
        }
        const int n = nbase + tid;
        idxf[n] = (float)I1;
        const bool flagged = (M2 - M1 <= MARGIN);
        float lsum = 0.f;
        if (flagged) {
            int p = atomicAdd(cnt, 1);
            wl[p] = n;
        } else {
            // unflagged: approx argmin provably == numpy argmin -> finalize row
            const float* e = emb + (size_t)I1 * DDIM;
            float* op = out + (size_t)b * DSP + s0 + tid;
#pragma unroll
            for (int d = 0; d < DDIM; ++d) {
                float qv = e[d];
                op[(size_t)d * SPAT] = qv;
                float df = qv - zrow[tid * ZPAD + d];
                lsum = fmaf(df, df, lsum);
            }
        }
#pragma unroll
        for (int off = 32; off > 0; off >>= 1)
            lsum += __shfl_down(lsum, off, 64);
        if (tid == 0)
            atomicAdd(loss, lsum * (1.25f / 4194304.0f));
    }
}

// K4: exact rescan of flagged rows (bit-exact numpy f32 replica), 4-way ILP; finalize zq+loss
__global__ void vq_rescan_kernel(const float* __restrict__ z, const float* __restrict__ emb,
                                 const float* __restrict__ e2, const float* __restrict__ h_,
                                 const int* __restrict__ cnt, const int* __restrict__ wl,
                                 float* __restrict__ out, float* __restrict__ loss,
                                 float* __restrict__ idxf)
{
    const int lane = threadIdx.x & 63;
    int gw = (blockIdx.x * blockDim.x + threadIdx.x) >> 6;
    const int count = *cnt;
    for (; gw < count; gw += 1024) {
        const int n = wl[gw];
        const int b = n >> 15, s = n & (SPAT - 1);
        const float* zp = z + (size_t)b * DSP + s;
        float zv[DDIM];
#pragma unroll
        for (int d = 0; d < DDIM; ++d) zv[d] = zp[(size_t)d * SPAT];
        const float sn = np_sumsq64(zv);

        float best = 3.0e38f; int bidx = 0;
        const int k0 = lane * 16;
#pragma unroll
        for (int q = 0; q < 4; ++q) {
            // 4 independent sequential-d chains (bit-identical order per chain)
            const float4* p0 = (const float4*)(e2 + (size_t)(k0 + 4 * q + 0) * DDIM);
            const float4* p1 = (const float4*)(e2 + (size_t)(k0 + 4 * q + 1) * DDIM);
            const float4* p2 = (const float4*)(e2 + (size_t)(k0 + 4 * q + 2) * DDIM);
            const float4* p3 = (const float4*)(e2 + (size_t)(k0 + 4 * q + 3) * DDIM);
            float a0 = 0.f, a1 = 0.f, a2 = 0.f, a3 = 0.f;
#pragma unroll
            for (int dq = 0; dq < 16; ++dq) {
                float4 v0 = p0[dq], v1 = p1[dq], v2 = p2[dq], v3 = p3[dq];
                float z0 = zv[4 * dq], z1 = zv[4 * dq + 1], z2 = zv[4 * dq + 2], z3 = zv[4 * dq + 3];
                a0 = fmaf(v0.x, z0, a0); a1 = fmaf(v1.x, z0, a1); a2 = fmaf(v2.x, z0, a2); a3 = fmaf(v3.x, z0, a3);
                a0 = fmaf(v0.y, z1, a0); a1 = fmaf(v1.y, z1, a1); a2 = fmaf(v2.y, z1, a2); a3 = fmaf(v3.y, z1, a3);
                a0 = fmaf(v0.z, z2, a0); a1 = fmaf(v1.z, z2, a1); a2 = fmaf(v2.z, z2, a2); a3 = fmaf(v3.z, z2, a3);
                a0 = fmaf(v0.w, z3, a0); a1 = fmaf(v1.w, z3, a1); a2 = fmaf(v2.w, z3, a2); a3 = fmaf(v3.w, z3, a3);
            }
            const int kb = k0 + 4 * q;
            float d0 = (sn + h_[kb + 0]) - a0;
            float d1 = (sn + h_[kb + 1]) - a1;
            float d2 = (sn + h_[kb + 2]) - a2;
            float d3 = (sn + h_[kb + 3]) - a3;
            if (d0 < best) { best = d0; bidx = kb + 0; }
            if (d1 < best) { best = d1; bidx = kb + 1; }
            if (d2 < best) { best = d2; bidx = kb + 2; }
            if (d3 < best) { best = d3; bidx = kb + 3; }
        }
#pragma unroll
        for (int off = 32; off > 0; off >>= 1) {
            float ob = __shfl_down(best, off, 64);
            int   oi = __shfl_down(bidx, off, 64);
            if (ob < best || (ob == best && oi < bidx)) { best = ob; bidx = oi; }
        }
        bidx = __shfl(bidx, 0, 64);

        if (lane == 0) idxf[n] = (float)bidx;
        // finalize row: zq write + loss partial (lane == d)
        float q_d = emb[(size_t)bidx * DDIM + lane];
        float z_d = zp[(size_t)lane * SPAT];
        out[(size_t)b * DSP + s + (size_t)lane * SPAT] = q_d;
        float df = q_d - z_d;
        float lsum = df * df;
#pragma unroll
        for (int off = 32; off > 0; off >>= 1)
            lsum += __shfl_down(lsum, off, 64);
        if (lane == 0)
            atomicAdd(loss, lsum * (1.25f / 4194304.0f));
    }
}

extern "C" void kernel_launch(void* const* d_in, const int* in_sizes, int n_in,
                              void* d_out, int out_size, void* d_ws, size_t ws_size,
                              hipStream_t stream) {
    const float* z   = (const float*)d_in[0];   // [2, 64, 32, 32, 32]
    const float* emb = (const float*)d_in[1];   // [1024, 64]
    float* out  = (float*)d_out;                // z_q (4194304) | loss (1) | indices (65536)
    float* loss = out + 4194304;
    float* idxf = out + 4194305;

    float* h_  = (float*)d_ws;                  // [1024]
    float* e2_ = h_ + KDIM;                     // [1024*64]
    __half* eh_ = (__half*)(e2_ + KDIM * DDIM); // [1024*64] halves
    __half* el_ = eh_ + KDIM * DDIM;            // [1024*64] halves
    int* cnt = (int*)(el_ + KDIM * DDIM);       // [1]
    int* wl  = cnt + 1;                         // [65536]

    hipMemsetAsync(loss, 0, sizeof(float), stream);
    hipMemsetAsync(cnt, 0, sizeof(int), stream);
    vq_prep_e<<<KDIM / 256, 256, 0, stream>>>(emb, e2_, h_, eh_, el_);
    vq_mfma_kernel<<<NVEC / 64, 256, 0, stream>>>(z, emb, eh_, el_, h_, out, loss, idxf, cnt, wl);
    vq_rescan_kernel<<<256, 256, 0, stream>>>(z, emb, e2_, h_, cnt, wl, out, loss, idxf);
}

// Round 8
// 122.776 us; speedup vs baseline: 1.5648x; 1.5009x over previous
//
#include <hip/hip_runtime.h>
#include <hip/hip_fp16.h>

#define KDIM 1024
#define DDIM 64
#define SPAT 32768
#define NVEC 65536
#define DSP  (DDIM * SPAT)          // 2097152
#define MARGIN 4.0e-5f              // > 2*eps(approx vs numpy-f32 dist)
#define ZPAD 69
#define QCAP 3072

typedef _Float16 half8 __attribute__((ext_vector_type(8)));
typedef float floatx4 __attribute__((ext_vector_type(4)));

__device__ __forceinline__ float opaque(float x) { asm volatile("" : "+v"(x)); return x; }

// Bitwise replica of np.add.reduce pairwise base case over fl(x[d]^2), d=0..63 (R3-proven)
__device__ __forceinline__ float np_sumsq64(const float* x) {
    float r8[8];
#pragma unroll
    for (int j = 0; j < 8; ++j) r8[j] = opaque(x[1 + j] * x[1 + j]);
#pragma unroll
    for (int i = 8; i < 56; i += 8) {
#pragma unroll
        for (int j = 0; j < 8; ++j) r8[j] += opaque(x[1 + i + j] * x[1 + i + j]);
    }
    float res = ((r8[0] + r8[1]) + (r8[2] + r8[3])) + ((r8[4] + r8[5]) + (r8[6] + r8[7]));
#pragma unroll
    for (int m = 57; m < 64; ++m) res += opaque(x[m] * x[m]);
    return opaque(x[0] * x[0]) + res;
}

// K1: h = np-f32 ||e||^2, e2 = 2e (exact), eh/el = fp16 hi/lo of e*1024
__global__ void vq_prep_e(const float* __restrict__ emb, float* __restrict__ e2,
                          float* __restrict__ h, __half* __restrict__ eh,
                          __half* __restrict__ el) {
    int k = blockIdx.x * blockDim.x + threadIdx.x;
    if (k >= KDIM) return;
    float e[DDIM];
#pragma unroll
    for (int d = 0; d < DDIM; ++d) {
        e[d] = emb[k * DDIM + d];
        e2[k * DDIM + d] = e[d] + e[d];
    }
    h[k] = np_sumsq64(e);
#pragma unroll
    for (int j = 0; j < 8; ++j) {
        half8 vh, vl;
#pragma unroll
        for (int u = 0; u < 8; ++u) {
            float es = e[8 * j + u] * 1024.0f;   // exact scale
            _Float16 hi = (_Float16)es;
            vh[u] = hi; vl[u] = (_Float16)(es - (float)hi);
        }
        ((half8*)(eh + (size_t)k * DDIM))[j] = vh;
        ((half8*)(el + (size_t)k * DDIM))[j] = vl;
    }
}

// K2: fused scan. Phase1: MFMA approx min. Phase2: MFMA re-scan -> candidate queue.
// Phase3: bit-exact numpy-f32 rescore of candidates. Phase4: per-row exact argmin + epilogue.
__global__ __launch_bounds__(256, 2) void vq_mfma_kernel(
    const float* __restrict__ z, const float* __restrict__ emb,
    const __half* __restrict__ eh_, const __half* __restrict__ el_,
    const float* __restrict__ h_, const float* __restrict__ e2_,
    float* __restrict__ out, float* __restrict__ loss, float* __restrict__ idxf)
{
    __shared__ float zrow[64 * ZPAD];     // [row][d]
    __shared__ float lds_sn[64];
    __shared__ float Lm1[16][64];
    __shared__ float m1f[64];
    __shared__ int   qcnt;
    __shared__ unsigned short      qk[QCAP];
    __shared__ unsigned char       qn[QCAP];
    __shared__ unsigned long long  qres[QCAP];

    const int tid = threadIdx.x, l = tid & 63, w = tid >> 6;
    const int nbase = blockIdx.x * 64;
    const int b = nbase >> 15, s0 = nbase & (SPAT - 1);
    const int col16 = l & 15, g16 = l >> 4;
    const float* zbase = z + (size_t)b * DSP + s0;

    if (tid == 0) qcnt = 0;

    // stage 64 z-rows: wave w loads d in [w*16, w*16+16), lane = row (coalesced 256B)
    {
        const int dbase = w * 16;
#pragma unroll
        for (int j = 0; j < 16; ++j)
            zrow[l * ZPAD + dbase + j] = zbase[(size_t)(dbase + j) * SPAT + l];
    }
    __syncthreads();

    if (tid < 64) lds_sn[tid] = np_sumsq64(&zrow[tid * ZPAD]);

    // resident Z fragments: zf[nc][kp][hi/lo]
    half8 zf[4][2][2];
#pragma unroll
    for (int nc = 0; nc < 4; ++nc) {
        const int r = nc * 16 + col16;
#pragma unroll
        for (int kp = 0; kp < 2; ++kp) {
            const int d0 = g16 * 8 + kp * 32;
            half8 vh, vl;
#pragma unroll
            for (int u = 0; u < 8; ++u) {
                float x = zrow[r * ZPAD + d0 + u];
                _Float16 hi = (_Float16)x;
                vh[u] = hi; vl[u] = (_Float16)(x - (float)hi);
            }
            zf[nc][kp][0] = vh; zf[nc][kp][1] = vl;
        }
    }
    __syncthreads();

    float snv[4];
#pragma unroll
    for (int nc = 0; nc < 4; ++nc) snv[nc] = lds_sn[nc * 16 + col16];

    const int myk0 = w * 256;

    // ---- phase 1: approx min per column ----
    float m1[4];
#pragma unroll
    for (int nc = 0; nc < 4; ++nc) m1[nc] = 3.0e38f;

    for (int t = 0; t < 16; ++t) {
        const int krow0 = myk0 + t * 16;
        const size_t eoff = (size_t)(krow0 + col16) * DDIM + g16 * 8;
        half8 ef0h = *(const half8*)(eh_ + eoff);
        half8 ef1h = *(const half8*)(eh_ + eoff + 32);
        half8 ef0l = *(const half8*)(el_ + eoff);
        half8 ef1l = *(const half8*)(el_ + eoff + 32);
        floatx4 hv = *(const floatx4*)(h_ + krow0 + g16 * 4);
#pragma unroll
        for (int nc = 0; nc < 4; ++nc) {
            floatx4 acc = {0.f, 0.f, 0.f, 0.f};
            acc = __builtin_amdgcn_mfma_f32_16x16x32_f16(ef0h, zf[nc][0][0], acc, 0, 0, 0);
            acc = __builtin_amdgcn_mfma_f32_16x16x32_f16(ef1h, zf[nc][1][0], acc, 0, 0, 0);
            acc = __builtin_amdgcn_mfma_f32_16x16x32_f16(ef0h, zf[nc][0][1], acc, 0, 0, 0);
            acc = __builtin_amdgcn_mfma_f32_16x16x32_f16(ef1h, zf[nc][1][1], acc, 0, 0, 0);
            acc = __builtin_amdgcn_mfma_f32_16x16x32_f16(ef0l, zf[nc][0][0], acc, 0, 0, 0);
            acc = __builtin_amdgcn_mfma_f32_16x16x32_f16(ef1l, zf[nc][1][0], acc, 0, 0, 0);
#pragma unroll
            for (int j = 0; j < 4; ++j) {
                float dist = fmaf(-0.001953125f, acc[j], snv[nc] + hv[j]);
                m1[nc] = fminf(m1[nc], dist);
            }
        }
    }
    const int slot = w * 4 + g16;
#pragma unroll
    for (int nc = 0; nc < 4; ++nc) Lm1[slot][nc * 16 + col16] = m1[nc];
    __syncthreads();

    if (tid < 64) {
        float M1 = Lm1[0][tid];
#pragma unroll
        for (int sI = 1; sI < 16; ++sI) M1 = fminf(M1, Lm1[sI][tid]);
        m1f[tid] = M1;
    }
    __syncthreads();

    // ---- phase 2: re-scan, push candidates within MARGIN of min ----
    float thr[4];
#pragma unroll
    for (int nc = 0; nc < 4; ++nc) thr[nc] = m1f[nc * 16 + col16] + MARGIN;

    for (int t = 0; t < 16; ++t) {
        const int krow0 = myk0 + t * 16;
        const size_t eoff = (size_t)(krow0 + col16) * DDIM + g16 * 8;
        half8 ef0h = *(const half8*)(eh_ + eoff);
        half8 ef1h = *(const half8*)(eh_ + eoff + 32);
        half8 ef0l = *(const half8*)(el_ + eoff);
        half8 ef1l = *(const half8*)(el_ + eoff + 32);
        floatx4 hv = *(const floatx4*)(h_ + krow0 + g16 * 4);
        const int rbase = krow0 + g16 * 4;
#pragma unroll
        for (int nc = 0; nc < 4; ++nc) {
            floatx4 acc = {0.f, 0.f, 0.f, 0.f};
            acc = __builtin_amdgcn_mfma_f32_16x16x32_f16(ef0h, zf[nc][0][0], acc, 0, 0, 0);
            acc = __builtin_amdgcn_mfma_f32_16x16x32_f16(ef1h, zf[nc][1][0], acc, 0, 0, 0);
            acc = __builtin_amdgcn_mfma_f32_16x16x32_f16(ef0h, zf[nc][0][1], acc, 0, 0, 0);
            acc = __builtin_amdgcn_mfma_f32_16x16x32_f16(ef1h, zf[nc][1][1], acc, 0, 0, 0);
            acc = __builtin_amdgcn_mfma_f32_16x16x32_f16(ef0l, zf[nc][0][0], acc, 0, 0, 0);
            acc = __builtin_amdgcn_mfma_f32_16x16x32_f16(ef1l, zf[nc][1][0], acc, 0, 0, 0);
#pragma unroll
            for (int j = 0; j < 4; ++j) {
                float dist = fmaf(-0.001953125f, acc[j], snv[nc] + hv[j]);
                if (dist <= thr[nc]) {
                    int p = atomicAdd(&qcnt, 1);
                    if (p < QCAP) {
                        qk[p] = (unsigned short)(rbase + j);
                        qn[p] = (unsigned char)(nc * 16 + col16);
                    }
                }
            }
        }
    }
    __syncthreads();

    const int qlen = min(qcnt, QCAP);

    // ---- phase 3: bit-exact numpy-f32 rescore of each candidate ----
    for (int i = tid; i < qlen; i += 256) {
        const int k = qk[i], r = qn[i];
        const float* zr = &zrow[r * ZPAD];
        const floatx4* ep = (const floatx4*)(e2_ + (size_t)k * DDIM);
        float acc = 0.f;
#pragma unroll
        for (int dq = 0; dq < 16; ++dq) {
            floatx4 v = ep[dq];
            acc = fmaf(v[0], zr[4 * dq + 0], acc);   // sequential ascending d from 0
            acc = fmaf(v[1], zr[4 * dq + 1], acc);
            acc = fmaf(v[2], zr[4 * dq + 2], acc);
            acc = fmaf(v[3], zr[4 * dq + 3], acc);
        }
        float t    = lds_sn[r] + h_[k];   // fl(sn + h)
        float dist = t - acc;             // fl(t - 2 z.e)
        unsigned int db = __float_as_uint(dist);   // dist > 0 always -> monotonic
        qres[i] = ((unsigned long long)db << 32) | (unsigned int)k;
    }
    __syncthreads();

    // ---- phase 4: per-row exact argmin (lowest dist, then lowest k) + epilogue ----
    if (tid < 64) {
        unsigned long long best = ~0ull;
        for (int i = 0; i < qlen; ++i)
            if (qn[i] == tid) best = min(best, qres[i]);
        const int I1 = (int)(best & 0xffffffffu);
        const int n = nbase + tid;
        idxf[n] = (float)I1;

        const float* e = emb + (size_t)I1 * DDIM;
        float* op = out + (size_t)b * DSP + s0 + tid;
        float lsum = 0.f;
#pragma unroll
        for (int d = 0; d < DDIM; ++d) {
            float qv = e[d];
            op[(size_t)d * SPAT] = qv;
            float df = qv - zrow[tid * ZPAD + d];
            lsum = fmaf(df, df, lsum);
        }
#pragma unroll
        for (int off = 32; off > 0; off >>= 1)
            lsum += __shfl_down(lsum, off, 64);
        if (tid == 0)
            atomicAdd(loss, lsum * (1.25f / 4194304.0f));
    }
}

extern "C" void kernel_launch(void* const* d_in, const int* in_sizes, int n_in,
                              void* d_out, int out_size, void* d_ws, size_t ws_size,
                              hipStream_t stream) {
    const float* z   = (const float*)d_in[0];   // [2, 64, 32, 32, 32]
    const float* emb = (const float*)d_in[1];   // [1024, 64]
    float* out  = (float*)d_out;                // z_q (4194304) | loss (1) | indices (65536)
    float* loss = out + 4194304;
    float* idxf = out + 4194305;

    float* h_  = (float*)d_ws;                  // [1024]
    float* e2_ = h_ + KDIM;                     // [1024*64]
    __half* eh_ = (__half*)(e2_ + KDIM * DDIM); // [1024*64] halves
    __half* el_ = eh_ + KDIM * DDIM;            // [1024*64] halves

    hipMemsetAsync(loss, 0, sizeof(float), stream);
    vq_prep_e<<<KDIM / 256, 256, 0, stream>>>(emb, e2_, h_, eh_, el_);
    vq_mfma_kernel<<<NVEC / 64, 256, 0, stream>>>(z, emb, eh_, el_, h_, e2_, out, loss, idxf);
}

// Round 9
// 71.858 us; speedup vs baseline: 2.6736x; 1.7086x over previous
//
#include <hip/hip_runtime.h>
#include <hip/hip_fp16.h>

#define KDIM 1024
#define DDIM 64
#define SPAT 32768
#define NVEC 65536
#define DSP  (DDIM * SPAT)          // 2097152
#define MARGIN 5.0e-4f              // > 2*eps(hi-only approx vs numpy-f32 dist), worst-case row
#define ZPAD 69
#define QCAP 1536

typedef _Float16 half8 __attribute__((ext_vector_type(8)));
typedef float floatx4 __attribute__((ext_vector_type(4)));

__device__ __forceinline__ float opaque(float x) { asm volatile("" : "+v"(x)); return x; }

// Bitwise replica of np.add.reduce pairwise base case over fl(x[d]^2), d=0..63 (R3-proven)
__device__ __forceinline__ float np_sumsq64(const float* x) {
    float r8[8];
#pragma unroll
    for (int j = 0; j < 8; ++j) r8[j] = opaque(x[1 + j] * x[1 + j]);
#pragma unroll
    for (int i = 8; i < 56; i += 8) {
#pragma unroll
        for (int j = 0; j < 8; ++j) r8[j] += opaque(x[1 + i + j] * x[1 + i + j]);
    }
    float res = ((r8[0] + r8[1]) + (r8[2] + r8[3])) + ((r8[4] + r8[5]) + (r8[6] + r8[7]));
#pragma unroll
    for (int m = 57; m < 64; ++m) res += opaque(x[m] * x[m]);
    return opaque(x[0] * x[0]) + res;
}

// K1: h = np-f32 ||e||^2, e2 = 2e (exact), eh = fp16(e*1024) hi plane only
__global__ void vq_prep_e(const float* __restrict__ emb, float* __restrict__ e2,
                          float* __restrict__ h, __half* __restrict__ eh) {
    int k = blockIdx.x * blockDim.x + threadIdx.x;
    if (k >= KDIM) return;
    float e[DDIM];
#pragma unroll
    for (int d = 0; d < DDIM; ++d) {
        e[d] = emb[k * DDIM + d];
        e2[k * DDIM + d] = e[d] + e[d];
    }
    h[k] = np_sumsq64(e);
#pragma unroll
    for (int j = 0; j < 8; ++j) {
        half8 vh;
#pragma unroll
        for (int u = 0; u < 8; ++u)
            vh[u] = (_Float16)(e[8 * j + u] * 1024.0f);   // exact scale, fp16 round
        ((half8*)(eh + (size_t)k * DDIM))[j] = vh;
    }
}

// K2: fused. P1: hi-only MFMA approx min. P2: re-scan -> candidate queue (margin 5e-4).
// P3: bit-exact numpy-f32 rescore. P4: per-row exact argmin + epilogue.
__global__ __launch_bounds__(256, 4) void vq_mfma_kernel(
    const float* __restrict__ z, const float* __restrict__ emb,
    const __half* __restrict__ eh_, const float* __restrict__ h_,
    const float* __restrict__ e2_, float* __restrict__ out,
    float* __restrict__ loss, float* __restrict__ idxf)
{
    __shared__ float zrow[64 * ZPAD];     // 17.7 KB
    __shared__ float lds_sn[64];
    __shared__ float Lm1[16][64];         // 4 KB
    __shared__ float m1f[64];
    __shared__ int   qcnt;
    __shared__ unsigned short      qk[QCAP];   // 3 KB
    __shared__ unsigned char       qn[QCAP];   // 1.5 KB
    __shared__ unsigned long long  qres[QCAP]; // 12 KB

    const int tid = threadIdx.x, l = tid & 63, w = tid >> 6;
    const int nbase = blockIdx.x * 64;
    const int b = nbase >> 15, s0 = nbase & (SPAT - 1);
    const int col16 = l & 15, g16 = l >> 4;
    const float* zbase = z + (size_t)b * DSP + s0;

    if (tid == 0) qcnt = 0;

    // stage 64 z-rows: wave w loads d in [w*16, w*16+16), lane = row (coalesced 256B)
    {
        const int dbase = w * 16;
#pragma unroll
        for (int j = 0; j < 16; ++j)
            zrow[l * ZPAD + dbase + j] = zbase[(size_t)(dbase + j) * SPAT + l];
    }
    __syncthreads();

    if (tid < 64) lds_sn[tid] = np_sumsq64(&zrow[tid * ZPAD]);

    // resident Z hi fragments: zf[nc][kp]
    half8 zf[4][2];
#pragma unroll
    for (int nc = 0; nc < 4; ++nc) {
        const int r = nc * 16 + col16;
#pragma unroll
        for (int kp = 0; kp < 2; ++kp) {
            const int d0 = g16 * 8 + kp * 32;
            half8 vh;
#pragma unroll
            for (int u = 0; u < 8; ++u)
                vh[u] = (_Float16)zrow[r * ZPAD + d0 + u];
            zf[nc][kp] = vh;
        }
    }
    __syncthreads();

    float snv[4];
#pragma unroll
    for (int nc = 0; nc < 4; ++nc) snv[nc] = lds_sn[nc * 16 + col16];

    const int myk0 = w * 256;

    // ---- phase 1: approx min per column (hi-only, prefetched) ----
    float m1[4];
#pragma unroll
    for (int nc = 0; nc < 4; ++nc) m1[nc] = 3.0e38f;
    {
        size_t eoff = (size_t)(myk0 + col16) * DDIM + g16 * 8;
        half8 ef0 = *(const half8*)(eh_ + eoff);
        half8 ef1 = *(const half8*)(eh_ + eoff + 32);
        floatx4 hv = *(const floatx4*)(h_ + myk0 + g16 * 4);
        for (int t = 0; t < 16; ++t) {
            half8 cf0 = ef0, cf1 = ef1; floatx4 chv = hv;
            if (t < 15) {
                const size_t e2off = (size_t)(myk0 + (t + 1) * 16 + col16) * DDIM + g16 * 8;
                ef0 = *(const half8*)(eh_ + e2off);
                ef1 = *(const half8*)(eh_ + e2off + 32);
                hv  = *(const floatx4*)(h_ + myk0 + (t + 1) * 16 + g16 * 4);
            }
#pragma unroll
            for (int nc = 0; nc < 4; ++nc) {
                floatx4 acc = {0.f, 0.f, 0.f, 0.f};
                acc = __builtin_amdgcn_mfma_f32_16x16x32_f16(cf0, zf[nc][0], acc, 0, 0, 0);
                acc = __builtin_amdgcn_mfma_f32_16x16x32_f16(cf1, zf[nc][1], acc, 0, 0, 0);
#pragma unroll
                for (int j = 0; j < 4; ++j) {
                    float dist = fmaf(-0.001953125f, acc[j], snv[nc] + chv[j]);
                    m1[nc] = fminf(m1[nc], dist);
                }
            }
        }
    }
    const int slot = w * 4 + g16;
#pragma unroll
    for (int nc = 0; nc < 4; ++nc) Lm1[slot][nc * 16 + col16] = m1[nc];
    __syncthreads();

    if (tid < 64) {
        float M1 = Lm1[0][tid];
#pragma unroll
        for (int sI = 1; sI < 16; ++sI) M1 = fminf(M1, Lm1[sI][tid]);
        m1f[tid] = M1;
    }
    __syncthreads();

    // ---- phase 2: re-scan, push candidates within MARGIN of min ----
    float thr[4];
#pragma unroll
    for (int nc = 0; nc < 4; ++nc) thr[nc] = m1f[nc * 16 + col16] + MARGIN;
    {
        size_t eoff = (size_t)(myk0 + col16) * DDIM + g16 * 8;
        half8 ef0 = *(const half8*)(eh_ + eoff);
        half8 ef1 = *(const half8*)(eh_ + eoff + 32);
        floatx4 hv = *(const floatx4*)(h_ + myk0 + g16 * 4);
        for (int t = 0; t < 16; ++t) {
            half8 cf0 = ef0, cf1 = ef1; floatx4 chv = hv;
            if (t < 15) {
                const size_t e2off = (size_t)(myk0 + (t + 1) * 16 + col16) * DDIM + g16 * 8;
                ef0 = *(const half8*)(eh_ + e2off);
                ef1 = *(const half8*)(eh_ + e2off + 32);
                hv  = *(const floatx4*)(h_ + myk0 + (t + 1) * 16 + g16 * 4);
            }
            const int rbase = myk0 + t * 16 + g16 * 4;
#pragma unroll
            for (int nc = 0; nc < 4; ++nc) {
                floatx4 acc = {0.f, 0.f, 0.f, 0.f};
                acc = __builtin_amdgcn_mfma_f32_16x16x32_f16(cf0, zf[nc][0], acc, 0, 0, 0);
                acc = __builtin_amdgcn_mfma_f32_16x16x32_f16(cf1, zf[nc][1], acc, 0, 0, 0);
#pragma unroll
                for (int j = 0; j < 4; ++j) {
                    float dist = fmaf(-0.001953125f, acc[j], snv[nc] + chv[j]);
                    if (dist <= thr[nc]) {
                        int p = atomicAdd(&qcnt, 1);
                        if (p < QCAP) {
                            qk[p] = (unsigned short)(rbase + j);
                            qn[p] = (unsigned char)(nc * 16 + col16);
                        }
                    }
                }
            }
        }
    }
    __syncthreads();

    const int qlen = min(qcnt, QCAP);

    // ---- phase 3: bit-exact numpy-f32 rescore of each candidate ----
    for (int i = tid; i < qlen; i += 256) {
        const int k = qk[i], r = qn[i];
        const float* zr = &zrow[r * ZPAD];
        const floatx4* ep = (const floatx4*)(e2_ + (size_t)k * DDIM);
        float acc = 0.f;
#pragma unroll
        for (int dq = 0; dq < 16; ++dq) {
            floatx4 v = ep[dq];
            acc = fmaf(v[0], zr[4 * dq + 0], acc);   // sequential ascending d from 0
            acc = fmaf(v[1], zr[4 * dq + 1], acc);
            acc = fmaf(v[2], zr[4 * dq + 2], acc);
            acc = fmaf(v[3], zr[4 * dq + 3], acc);
        }
        float tt   = lds_sn[r] + h_[k];   // fl(sn + h)
        float dist = tt - acc;            // fl(t - 2 z.e)
        unsigned int db = __float_as_uint(dist);   // dist > 0 -> monotonic bits
        qres[i] = ((unsigned long long)db << 32) | (unsigned int)k;
    }
    __syncthreads();

    // ---- phase 4: per-row exact argmin (lowest dist, then lowest k) + epilogue ----
    if (tid < 64) {
        unsigned long long best = ~0ull;
        for (int i = 0; i < qlen; ++i)
            if (qn[i] == tid) best = min(best, qres[i]);
        const int I1 = (int)(best & 0xffffffffu);
        const int n = nbase + tid;
        idxf[n] = (float)I1;

        const float* e = emb + (size_t)I1 * DDIM;
        float* op = out + (size_t)b * DSP + s0 + tid;
        float lsum = 0.f;
#pragma unroll
        for (int d = 0; d < DDIM; ++d) {
            float qv = e[d];
            op[(size_t)d * SPAT] = qv;
            float df = qv - zrow[tid * ZPAD + d];
            lsum = fmaf(df, df, lsum);
        }
#pragma unroll
        for (int off = 32; off > 0; off >>= 1)
            lsum += __shfl_down(lsum, off, 64);
        if (tid == 0)
            atomicAdd(loss, lsum * (1.25f / 4194304.0f));
    }
}

extern "C" void kernel_launch(void* const* d_in, const int* in_sizes, int n_in,
                              void* d_out, int out_size, void* d_ws, size_t ws_size,
                              hipStream_t stream) {
    const float* z   = (const float*)d_in[0];   // [2, 64, 32, 32, 32]
    const float* emb = (const float*)d_in[1];   // [1024, 64]
    float* out  = (float*)d_out;                // z_q (4194304) | loss (1) | indices (65536)
    float* loss = out + 4194304;
    float* idxf = out + 4194305;

    float* h_  = (float*)d_ws;                  // [1024]
    float* e2_ = h_ + KDIM;                     // [1024*64]
    __half* eh_ = (__half*)(e2_ + KDIM * DDIM); // [1024*64] halves

    hipMemsetAsync(loss, 0, sizeof(float), stream);
    vq_prep_e<<<KDIM / 256, 256, 0, stream>>>(emb, e2_, h_, eh_);
    vq_mfma_kernel<<<NVEC / 64, 256, 0, stream>>>(z, emb, eh_, h_, e2_, out, loss, idxf);
}